// Round 1
// baseline (615.364 us; speedup 1.0000x reference)
//
#include <hip/hip_runtime.h>
#include <hip/hip_bf16.h>

// Phase 0: zero-init the per-node key array (ws is poisoned 0xAA each call).
__global__ void la_init_keys(unsigned long long* __restrict__ keys, int n) {
    int i = blockIdx.x * blockDim.x + threadIdx.x;
    if (i < n) keys[i] = 0ull;
}

// Phase 1: one thread per event. Pack (t, pos) into a 64-bit lexicographic key
// and atomicMax into keys[index[e]].
//   orderable(t): flip sign bit for t>=0, bitwise-not for t<0 -> monotone in t.
//   key = orderable << 32 | pos  -> max picks max t, ties broken by max pos,
//   exactly matching the reference's two-stage segment_max.
__global__ void la_scan_events(const int* __restrict__ index,
                               const float* __restrict__ t,
                               unsigned long long* __restrict__ keys,
                               int E) {
    int i = blockIdx.x * blockDim.x + threadIdx.x;
    if (i < E) {
        float tv = t[i];
        unsigned ub = __float_as_uint(tv);
        unsigned ord = (ub & 0x80000000u) ? ~ub : (ub | 0x80000000u);
        unsigned long long key = ((unsigned long long)ord << 32) | (unsigned)i;
        int node = index[i];
        atomicMax(&keys[node], key);  // device-scope by default on CDNA
    }
}

// Phase 2: gather winning msg rows. vecPerRow = D/4 float4 lanes per row;
// consecutive threads cover one row -> 512B contiguous read + coalesced write.
// key==0 means empty node -> write zeros.
__global__ void la_gather(const unsigned long long* __restrict__ keys,
                          const float4* __restrict__ msg,
                          float4* __restrict__ out,
                          int N, int vecPerRow) {
    long long gid = (long long)blockIdx.x * blockDim.x + threadIdx.x;
    int row = (int)(gid / vecPerRow);
    int col = (int)(gid - (long long)row * vecPerRow);
    if (row < N) {
        unsigned long long key = keys[row];
        float4 v = make_float4(0.f, 0.f, 0.f, 0.f);
        if (key != 0ull) {
            unsigned pos = (unsigned)(key & 0xFFFFFFFFull);
            v = msg[(long long)pos * vecPerRow + col];
        }
        out[(long long)row * vecPerRow + col] = v;
    }
}

extern "C" void kernel_launch(void* const* d_in, const int* in_sizes, int n_in,
                              void* d_out, int out_size, void* d_ws, size_t ws_size,
                              hipStream_t stream) {
    const float* msg  = (const float*)d_in[0];
    const int*   index = (const int*)d_in[1];   // harness delivers integer inputs as int32
    const float* t    = (const float*)d_in[2];
    // d_in[3] = dim_size scalar (unused; derive from sizes)

    const int E = in_sizes[1];                 // number of events
    const int D = in_sizes[0] / E;             // feature dim (128)
    const int N = out_size / D;                // number of nodes
    const int vecPerRow = D / 4;               // float4 lanes per row

    unsigned long long* keys = (unsigned long long*)d_ws;  // N * 8 bytes

    {
        int threads = 256, blocks = (N + threads - 1) / threads;
        la_init_keys<<<blocks, threads, 0, stream>>>(keys, N);
    }
    {
        int threads = 256, blocks = (E + threads - 1) / threads;
        la_scan_events<<<blocks, threads, 0, stream>>>(index, t, keys, E);
    }
    {
        long long total = (long long)N * vecPerRow;
        int threads = 256;
        long long blocks = (total + threads - 1) / threads;
        la_gather<<<(int)blocks, threads, 0, stream>>>(keys, (const float4*)msg,
                                                       (float4*)d_out, N, vecPerRow);
    }
}

// Round 3
// 606.560 us; speedup vs baseline: 1.0145x; 1.0145x over previous
//
#include <hip/hip_runtime.h>
#include <hip/hip_bf16.h>

// ---------------------------------------------------------------------------
// LastAggregator: per-node argmax over events keyed lexicographically by
// (t, position), then gather the winning 512B msg row.
// key = orderable(t) << 32 | pos ; atomicMax per event ; key==0 => empty node.
// ---------------------------------------------------------------------------

// native vector type: __builtin_nontemporal_* rejects HIP_vector_type<float,4>
typedef float f4 __attribute__((ext_vector_type(4)));

// Phase 0: zero-init the per-node key array (ws is poisoned 0xAA each call).
__global__ void la_init_keys(unsigned long long* __restrict__ keys, int n) {
    int i = blockIdx.x * blockDim.x + threadIdx.x;
    if (i < n) keys[i] = 0ull;
}

__device__ __forceinline__ unsigned la_ord(float tv) {
    unsigned ub = __float_as_uint(tv);
    // monotone transform: t>=0 -> bits|0x80000000 ; t<0 -> ~bits
    return (ub & 0x80000000u) ? ~ub : (ub | 0x80000000u);
}

// Phase 1: two events per thread (float2/int2 vector loads), atomicMax per event.
__global__ void la_scan_events2(const int2* __restrict__ index2,
                                const float2* __restrict__ t2,
                                unsigned long long* __restrict__ keys,
                                int Epairs) {
    int i = blockIdx.x * blockDim.x + threadIdx.x;
    if (i < Epairs) {
        float2 tv = t2[i];
        int2   ix = index2[i];
        unsigned e0 = 2u * (unsigned)i;
        unsigned long long k0 = ((unsigned long long)la_ord(tv.x) << 32) | e0;
        unsigned long long k1 = ((unsigned long long)la_ord(tv.y) << 32) | (e0 + 1u);
        atomicMax(&keys[ix.x], k0);
        atomicMax(&keys[ix.y], k1);
    }
}

// tail (odd E) handled by scalar kernel over the remainder
__global__ void la_scan_tail(const int* __restrict__ index,
                             const float* __restrict__ t,
                             unsigned long long* __restrict__ keys,
                             int start, int E) {
    int i = start + blockIdx.x * blockDim.x + threadIdx.x;
    if (i < E) {
        unsigned long long k = ((unsigned long long)la_ord(t[i]) << 32) | (unsigned)i;
        atomicMax(&keys[index[i]], k);
    }
}

// Phase 2: gather winning msg rows. VEC f4 lanes per row (compile-time).
// Non-temporal: msg rows and out are touched exactly once -> bypass L2 reuse.
template <int VEC, int SHIFT>
__global__ void la_gather_v(const unsigned long long* __restrict__ keys,
                            const f4* __restrict__ msg,
                            f4* __restrict__ out,
                            int N) {
    long long gid = (long long)blockIdx.x * blockDim.x + threadIdx.x;
    int row = (int)(gid >> SHIFT);
    int col = (int)(gid & (VEC - 1));
    if (row < N) {
        unsigned long long key = keys[row];
        f4 v = (f4)0.0f;
        if (key != 0ull) {
            unsigned pos = (unsigned)(key & 0xFFFFFFFFull);
            v = __builtin_nontemporal_load(&msg[(long long)pos * VEC + col]);
        }
        __builtin_nontemporal_store(v, &out[(long long)row * VEC + col]);
    }
}

// generic fallback (runtime vecPerRow)
__global__ void la_gather_g(const unsigned long long* __restrict__ keys,
                            const f4* __restrict__ msg,
                            f4* __restrict__ out,
                            int N, int vecPerRow) {
    long long gid = (long long)blockIdx.x * blockDim.x + threadIdx.x;
    int row = (int)(gid / vecPerRow);
    int col = (int)(gid - (long long)row * vecPerRow);
    if (row < N) {
        unsigned long long key = keys[row];
        f4 v = (f4)0.0f;
        if (key != 0ull) {
            unsigned pos = (unsigned)(key & 0xFFFFFFFFull);
            v = __builtin_nontemporal_load(&msg[(long long)pos * vecPerRow + col]);
        }
        __builtin_nontemporal_store(v, &out[(long long)row * vecPerRow + col]);
    }
}

extern "C" void kernel_launch(void* const* d_in, const int* in_sizes, int n_in,
                              void* d_out, int out_size, void* d_ws, size_t ws_size,
                              hipStream_t stream) {
    const float* msg   = (const float*)d_in[0];
    const int*   index = (const int*)d_in[1];   // integer inputs delivered as int32
    const float* t     = (const float*)d_in[2];

    const int E = in_sizes[1];
    const int D = in_sizes[0] / E;       // 128
    const int N = out_size / D;          // 100000
    const int vecPerRow = D / 4;         // 32

    unsigned long long* keys = (unsigned long long*)d_ws;  // N * 8 bytes

    {
        int threads = 256, blocks = (N + threads - 1) / threads;
        la_init_keys<<<blocks, threads, 0, stream>>>(keys, N);
    }
    {
        int Epairs = E / 2;
        int threads = 256, blocks = (Epairs + threads - 1) / threads;
        if (blocks > 0)
            la_scan_events2<<<blocks, threads, 0, stream>>>(
                (const int2*)index, (const float2*)t, keys, Epairs);
        int tail = E - 2 * Epairs;
        if (tail > 0)
            la_scan_tail<<<1, 64, 0, stream>>>(index, t, keys, 2 * Epairs, E);
    }
    {
        long long total = (long long)N * vecPerRow;
        int threads = 256;
        int blocks = (int)((total + threads - 1) / threads);
        if (vecPerRow == 32)
            la_gather_v<32, 5><<<blocks, threads, 0, stream>>>(
                keys, (const f4*)msg, (f4*)d_out, N);
        else if (vecPerRow == 16)
            la_gather_v<16, 4><<<blocks, threads, 0, stream>>>(
                keys, (const f4*)msg, (f4*)d_out, N);
        else
            la_gather_g<<<blocks, threads, 0, stream>>>(
                keys, (const f4*)msg, (f4*)d_out, N, vecPerRow);
    }
}